// Round 1
// baseline (1902.000 us; speedup 1.0000x reference)
//
#include <hip/hip_runtime.h>
#include <hip/hip_bf16.h>

#define DIM 2048
#define INTER 1408
#define NEXP 16
#define NTOK 8192
#define SINTER 2816

typedef __attribute__((ext_vector_type(8))) short bf16x8;
typedef __attribute__((ext_vector_type(4))) float f32x4;
typedef __attribute__((ext_vector_type(4))) unsigned short u16x4;
typedef __attribute__((ext_vector_type(8))) unsigned short u16x8;

__device__ __forceinline__ unsigned short f2bf(float f) {
    union { float f; unsigned u; } a; a.f = f;
    unsigned r = a.u + 0x7fffu + ((a.u >> 16) & 1u);
    return (unsigned short)(r >> 16);
}

__device__ __forceinline__ bf16x8 lds8(const unsigned short* p) {
    union { u16x4 h[2]; bf16x8 v; } t;
    t.h[0] = *(const u16x4*)p;
    t.h[1] = *(const u16x4*)(p + 4);
    return t.v;
}

// ---------------- gate + top2 routing ----------------
__global__ __launch_bounds__(256) void gate_topk(
    const float* __restrict__ x, const float* __restrict__ gw,
    int* __restrict__ counts, int* __restrict__ toklist, float* __restrict__ tokw) {
    int wave = threadIdx.x >> 6;
    int lane = threadIdx.x & 63;
    int tok  = blockIdx.x * 4 + wave;
    const float* xr = x + (size_t)tok * DIM;

    float part[NEXP];
#pragma unroll
    for (int e = 0; e < NEXP; ++e) part[e] = 0.f;
    for (int c = 0; c < DIM / 64; ++c) {
        int idx = c * 64 + lane;
        float xv = xr[idx];
#pragma unroll
        for (int e = 0; e < NEXP; ++e) part[e] += gw[e * DIM + idx] * xv;
    }
#pragma unroll
    for (int e = 0; e < NEXP; ++e) {
        float v = part[e];
#pragma unroll
        for (int off = 32; off; off >>= 1) v += __shfl_xor(v, off);
        part[e] = v;
    }
    // softmax over 16 + top-2 (all lanes redundantly; lane 0 writes)
    float mx = part[0];
#pragma unroll
    for (int e = 1; e < NEXP; ++e) mx = fmaxf(mx, part[e]);
    float Z = 0.f;
#pragma unroll
    for (int e = 0; e < NEXP; ++e) Z += expf(part[e] - mx);
    int i1 = 0; float m1 = part[0];
#pragma unroll
    for (int e = 1; e < NEXP; ++e) if (part[e] > m1) { m1 = part[e]; i1 = e; }
    int i2 = -1; float m2 = -1e30f;
#pragma unroll
    for (int e = 0; e < NEXP; ++e) if (e != i1 && part[e] > m2) { m2 = part[e]; i2 = e; }
    if (lane == 0) {
        float w1v = expf(m1 - mx) / Z;
        float w2v = expf(m2 - mx) / Z;
        int p1 = atomicAdd(&counts[i1], 1);
        toklist[i1 * NTOK + p1] = tok; tokw[i1 * NTOK + p1] = w1v;
        int p2 = atomicAdd(&counts[i2], 1);
        toklist[i2 * NTOK + p2] = tok; tokw[i2 * NTOK + p2] = w2v;
    }
}

// ---------------- prefix scan for compact h rows ----------------
__global__ void prefix_k(const int* __restrict__ counts, int* __restrict__ base) {
    if (threadIdx.x == 0) {
        int acc = 0;
        for (int e = 0; e < NEXP; ++e) { base[e] = acc; acc += counts[e]; }
        base[16] = acc;          // == 2*NTOK
        base[17] = acc + NTOK;
    }
}

// ---------------- GEMM1: h = silu(X W1^T) * (X W3^T), bf16 out ----------------
// grid: (INTER/128=11, 64 m-tiles, 18 "experts")  block: 256
__global__ __launch_bounds__(256, 2) void gemm1(
    const float* __restrict__ x,
    const float* __restrict__ w1, const float* __restrict__ w3,
    const float* __restrict__ sw1, const float* __restrict__ sw3,
    const int* __restrict__ counts, const int* __restrict__ base,
    const int* __restrict__ toklist, unsigned short* __restrict__ hbuf) {
    int e   = blockIdx.z;
    int cnt = (e < NEXP) ? counts[e] : NTOK;
    int m0  = blockIdx.y * 128;
    if (m0 >= cnt) return;
    int n0  = blockIdx.x * 128;
    const float* B1 = (e < NEXP) ? w1 + (size_t)e * INTER * DIM
                                 : sw1 + (size_t)(e - NEXP) * INTER * DIM;
    const float* B3 = (e < NEXP) ? w3 + (size_t)e * INTER * DIM
                                 : sw3 + (size_t)(e - NEXP) * INTER * DIM;
    const int* tl = toklist + e * NTOK;
    int hbase = base[e];

    __shared__ unsigned short As[128][40];
    __shared__ unsigned short Bs1[128][40];
    __shared__ unsigned short Bs3[128][40];

    int tid = threadIdx.x;
    int c4 = tid & 7;             // float4 slot within 32-wide K chunk
    const float* arow[4];
    bool valid[4];
    int rloc[4];
#pragma unroll
    for (int i = 0; i < 4; ++i) {
        int r = (tid >> 3) + 32 * i;
        rloc[i] = r;
        int grow = m0 + r;
        bool v = grow < cnt;
        valid[i] = v;
        int tok = v ? ((e < NEXP) ? tl[grow] : grow) : 0;
        arow[i] = x + (size_t)tok * DIM;
    }

    f32x4 acc1[4][4], acc3[4][4];
#pragma unroll
    for (int m = 0; m < 4; ++m)
#pragma unroll
        for (int n = 0; n < 4; ++n) {
            acc1[m][n] = (f32x4){0.f, 0.f, 0.f, 0.f};
            acc3[m][n] = (f32x4){0.f, 0.f, 0.f, 0.f};
        }

    int wave = tid >> 6, lane = tid & 63;
    int wr = wave >> 1, wc = wave & 1;
    int lrow = lane & 15, lk = (lane >> 4) * 8;

    for (int k0 = 0; k0 < DIM; k0 += 32) {
        // stage A (gathered token rows, f32 -> bf16)
#pragma unroll
        for (int i = 0; i < 4; ++i) {
            float4 v = valid[i] ? *(const float4*)(arow[i] + k0 + c4 * 4)
                                : make_float4(0.f, 0.f, 0.f, 0.f);
            u16x4 b = { f2bf(v.x), f2bf(v.y), f2bf(v.z), f2bf(v.w) };
            *(u16x4*)&As[rloc[i]][c4 * 4] = b;
        }
        // stage B1/B3 (weight rows n0+r, stride DIM)
#pragma unroll
        for (int i = 0; i < 4; ++i) {
            int r = (tid >> 3) + 32 * i;
            const float* p1 = B1 + (size_t)(n0 + r) * DIM + k0 + c4 * 4;
            float4 v = *(const float4*)p1;
            u16x4 b = { f2bf(v.x), f2bf(v.y), f2bf(v.z), f2bf(v.w) };
            *(u16x4*)&Bs1[r][c4 * 4] = b;
            const float* p3 = B3 + (size_t)(n0 + r) * DIM + k0 + c4 * 4;
            float4 v3 = *(const float4*)p3;
            u16x4 b3 = { f2bf(v3.x), f2bf(v3.y), f2bf(v3.z), f2bf(v3.w) };
            *(u16x4*)&Bs3[r][c4 * 4] = b3;
        }
        __syncthreads();
        bf16x8 af[4], b1f[4], b3f[4];
#pragma unroll
        for (int m = 0; m < 4; ++m) af[m] = lds8(&As[wr * 64 + m * 16 + lrow][lk]);
#pragma unroll
        for (int n = 0; n < 4; ++n) {
            b1f[n] = lds8(&Bs1[wc * 64 + n * 16 + lrow][lk]);
            b3f[n] = lds8(&Bs3[wc * 64 + n * 16 + lrow][lk]);
        }
#pragma unroll
        for (int m = 0; m < 4; ++m)
#pragma unroll
            for (int n = 0; n < 4; ++n) {
                acc1[m][n] = __builtin_amdgcn_mfma_f32_16x16x32_bf16(af[m], b1f[n], acc1[m][n], 0, 0, 0);
                acc3[m][n] = __builtin_amdgcn_mfma_f32_16x16x32_bf16(af[m], b3f[n], acc3[m][n], 0, 0, 0);
            }
        __syncthreads();
    }
    // epilogue: h = silu(c1)*c3 -> bf16 scratch
#pragma unroll
    for (int m = 0; m < 4; ++m)
#pragma unroll
        for (int n = 0; n < 4; ++n) {
#pragma unroll
            for (int i = 0; i < 4; ++i) {
                int row = wr * 64 + m * 16 + (lane >> 4) * 4 + i;
                int grow = m0 + row;
                if (grow < cnt) {
                    int col = n0 + wc * 64 + n * 16 + lrow;
                    float a = acc1[m][n][i];
                    float h = a / (1.f + expf(-a)) * acc3[m][n][i];
                    hbuf[(size_t)(hbase + grow) * INTER + col] = f2bf(h);
                }
            }
        }
}

// ---------------- GEMM2: y += (h W2^T) * tokw, atomic scatter ----------------
// grid: (DIM/128=16, 64 m-tiles, 18 "experts")  block: 256
__global__ __launch_bounds__(256, 2) void gemm2(
    const unsigned short* __restrict__ hbuf,
    const float* __restrict__ w2, const float* __restrict__ sw2,
    const int* __restrict__ counts, const int* __restrict__ base,
    const int* __restrict__ toklist, const float* __restrict__ tokw,
    float* __restrict__ out) {
    int e   = blockIdx.z;
    int cnt = (e < NEXP) ? counts[e] : NTOK;
    int m0  = blockIdx.y * 128;
    if (m0 >= cnt) return;
    int n0  = blockIdx.x * 128;
    const float* B; size_t bstride;
    if (e < NEXP) { B = w2 + (size_t)e * DIM * INTER; bstride = INTER; }
    else          { B = sw2 + (size_t)(e - NEXP) * INTER; bstride = SINTER; }
    int hbase = base[e];

    __shared__ unsigned short As[128][40];
    __shared__ unsigned short Bs[128][40];

    int tid = threadIdx.x;
    f32x4 acc[4][4];
#pragma unroll
    for (int m = 0; m < 4; ++m)
#pragma unroll
        for (int n = 0; n < 4; ++n) acc[m][n] = (f32x4){0.f, 0.f, 0.f, 0.f};

    int wave = tid >> 6, lane = tid & 63;
    int wr = wave >> 1, wc = wave & 1;
    int lrow = lane & 15, lk = (lane >> 4) * 8;
    int c8 = tid & 3;   // 16B slot for A (bf16) staging
    int c4 = tid & 7;   // float4 slot for B staging

    for (int k0 = 0; k0 < INTER; k0 += 32) {
        // stage A (bf16 h rows)
#pragma unroll
        for (int i = 0; i < 2; ++i) {
            int r = (tid >> 2) + 64 * i;
            int grow = m0 + r;
            u16x8 v;
            if (grow < cnt) {
                v = *(const u16x8*)(hbuf + (size_t)(hbase + grow) * INTER + k0 + c8 * 8);
            } else {
                v = (u16x8){0,0,0,0,0,0,0,0};
            }
            u16x4 lo = { v[0], v[1], v[2], v[3] };
            u16x4 hi = { v[4], v[5], v[6], v[7] };
            *(u16x4*)&As[r][c8 * 8]     = lo;
            *(u16x4*)&As[r][c8 * 8 + 4] = hi;
        }
        // stage B (f32 -> bf16)
#pragma unroll
        for (int i = 0; i < 4; ++i) {
            int r = (tid >> 3) + 32 * i;
            const float* p = B + (size_t)(n0 + r) * bstride + k0 + c4 * 4;
            float4 v = *(const float4*)p;
            u16x4 b = { f2bf(v.x), f2bf(v.y), f2bf(v.z), f2bf(v.w) };
            *(u16x4*)&Bs[r][c4 * 4] = b;
        }
        __syncthreads();
        bf16x8 af[4], bf[4];
#pragma unroll
        for (int m = 0; m < 4; ++m) af[m] = lds8(&As[wr * 64 + m * 16 + lrow][lk]);
#pragma unroll
        for (int n = 0; n < 4; ++n) bf[n] = lds8(&Bs[wc * 64 + n * 16 + lrow][lk]);
#pragma unroll
        for (int m = 0; m < 4; ++m)
#pragma unroll
            for (int n = 0; n < 4; ++n)
                acc[m][n] = __builtin_amdgcn_mfma_f32_16x16x32_bf16(af[m], bf[n], acc[m][n], 0, 0, 0);
        __syncthreads();
    }
    // epilogue: weighted atomic scatter into out
#pragma unroll
    for (int m = 0; m < 4; ++m) {
#pragma unroll
        for (int i = 0; i < 4; ++i) {
            int row = wr * 64 + m * 16 + (lane >> 4) * 4 + i;
            int grow = m0 + row;
            if (grow < cnt) {
                int tok; float w;
                if (e < NEXP) { tok = toklist[e * NTOK + grow]; w = tokw[e * NTOK + grow]; }
                else          { tok = grow; w = 1.f; }
                float* orow = out + (size_t)tok * DIM;
#pragma unroll
                for (int n = 0; n < 4; ++n) {
                    int col = n0 + wc * 64 + n * 16 + lrow;
                    unsafeAtomicAdd(&orow[col], acc[m][n][i] * w);
                }
            }
        }
    }
}

extern "C" void kernel_launch(void* const* d_in, const int* in_sizes, int n_in,
                              void* d_out, int out_size, void* d_ws, size_t ws_size,
                              hipStream_t stream) {
    const float* x   = (const float*)d_in[0];
    const float* gw  = (const float*)d_in[1];
    const float* w1  = (const float*)d_in[2];
    const float* w2  = (const float*)d_in[3];
    const float* w3  = (const float*)d_in[4];
    const float* sw1 = (const float*)d_in[5];
    const float* sw2 = (const float*)d_in[6];
    const float* sw3 = (const float*)d_in[7];
    float* out = (float*)d_out;

    char* ws = (char*)d_ws;
    int*   counts  = (int*)ws;                                   // 16 ints
    int*   base    = (int*)(ws + 128);                           // 18 ints
    int*   toklist = (int*)(ws + 4096);                          // 16*8192 ints
    float* tokw    = (float*)(ws + 4096 + NEXP * NTOK * 4);      // 16*8192 floats
    unsigned short* hbuf = (unsigned short*)(ws + (2u << 20));   // 32768*1408 bf16

    hipMemsetAsync(counts, 0, 64, stream);
    hipMemsetAsync(d_out, 0, (size_t)out_size * sizeof(float), stream);

    gate_topk<<<NTOK / 4, 256, 0, stream>>>(x, gw, counts, toklist, tokw);
    prefix_k<<<1, 64, 0, stream>>>(counts, base);
    gemm1<<<dim3(INTER / 128, NTOK / 128, 18), 256, 0, stream>>>(
        x, w1, w3, sw1, sw3, counts, base, toklist, hbuf);
    gemm2<<<dim3(DIM / 128, NTOK / 128, 18), 256, 0, stream>>>(
        hbuf, w2, sw2, counts, base, toklist, tokw, out);
}

// Round 2
// 1443.317 us; speedup vs baseline: 1.3178x; 1.3178x over previous
//
#include <hip/hip_runtime.h>
#include <hip/hip_bf16.h>

#define DIM 2048
#define INTER 1408
#define NEXP 16
#define NTOK 8192
#define SINTER 2816
#define BM 256
#define BN 128
#define BK 32

typedef __attribute__((ext_vector_type(8))) short bf16x8;
typedef __attribute__((ext_vector_type(4))) float f32x4;
typedef __attribute__((ext_vector_type(8))) unsigned short u16x8;

__device__ __forceinline__ unsigned short f2bf(float f) {
    union { float f; unsigned u; } a; a.f = f;
    unsigned r = a.u + 0x7fffu + ((a.u >> 16) & 1u);
    return (unsigned short)(r >> 16);
}

__device__ __forceinline__ void gload16(const void* g, void* lds) {
    __builtin_amdgcn_global_load_lds(
        (const __attribute__((address_space(1))) void*)g,
        (__attribute__((address_space(3))) void*)lds, 16, 0, 0);
}

// load 8 f32, convert, write 16B to LDS (matches gload16 lane layout)
__device__ __forceinline__ void stage_f32(const float* g, unsigned short* ldsdst) {
    float4 a = *(const float4*)g;
    float4 b = *(const float4*)(g + 4);
    u16x8 o = { f2bf(a.x), f2bf(a.y), f2bf(a.z), f2bf(a.w),
                f2bf(b.x), f2bf(b.y), f2bf(b.z), f2bf(b.w) };
    *(u16x8*)ldsdst = o;
}

// ---------------- f32 -> bf16 cast ----------------
__global__ __launch_bounds__(256) void cast_bf16(const float* __restrict__ s,
                                                 unsigned short* __restrict__ d,
                                                 long long n) {
    long long i = ((long long)blockIdx.x * 256 + threadIdx.x) * 8;
    if (i >= n) return;
    float4 a = *(const float4*)(s + i), b = *(const float4*)(s + i + 4);
    u16x8 o = { f2bf(a.x), f2bf(a.y), f2bf(a.z), f2bf(a.w),
                f2bf(b.x), f2bf(b.y), f2bf(b.z), f2bf(b.w) };
    *(u16x8*)(d + i) = o;
}

// ---------------- gate + top2 routing ----------------
__global__ __launch_bounds__(256) void gate_topk(
    const float* __restrict__ x, const float* __restrict__ gw,
    int* __restrict__ counts, int* __restrict__ toklist, float* __restrict__ tokw) {
    int wave = threadIdx.x >> 6;
    int lane = threadIdx.x & 63;
    int tok  = blockIdx.x * 4 + wave;
    const float* xr = x + (size_t)tok * DIM;

    float part[NEXP];
#pragma unroll
    for (int e = 0; e < NEXP; ++e) part[e] = 0.f;
#pragma unroll
    for (int c = 0; c < DIM / 256; ++c) {
        float4 xv = *(const float4*)(xr + c * 256 + lane * 4);
#pragma unroll
        for (int e = 0; e < NEXP; ++e) {
            float4 g = *(const float4*)(gw + e * DIM + c * 256 + lane * 4);
            part[e] += xv.x * g.x + xv.y * g.y + xv.z * g.z + xv.w * g.w;
        }
    }
#pragma unroll
    for (int e = 0; e < NEXP; ++e) {
        float v = part[e];
#pragma unroll
        for (int off = 32; off; off >>= 1) v += __shfl_xor(v, off);
        part[e] = v;
    }
    float mx = part[0];
#pragma unroll
    for (int e = 1; e < NEXP; ++e) mx = fmaxf(mx, part[e]);
    float Z = 0.f;
#pragma unroll
    for (int e = 0; e < NEXP; ++e) Z += expf(part[e] - mx);
    int i1 = 0; float m1 = part[0];
#pragma unroll
    for (int e = 1; e < NEXP; ++e) if (part[e] > m1) { m1 = part[e]; i1 = e; }
    int i2 = -1; float m2 = -1e30f;
#pragma unroll
    for (int e = 0; e < NEXP; ++e) if (e != i1 && part[e] > m2) { m2 = part[e]; i2 = e; }
    if (lane == 0) {
        float w1v = expf(m1 - mx) / Z;
        float w2v = expf(m2 - mx) / Z;
        int p1 = atomicAdd(&counts[i1], 1);
        toklist[i1 * NTOK + p1] = tok; tokw[i1 * NTOK + p1] = w1v;
        int p2 = atomicAdd(&counts[i2], 1);
        toklist[i2 * NTOK + p2] = tok; tokw[i2 * NTOK + p2] = w2v;
    }
}

__global__ void prefix_k(const int* __restrict__ counts, int* __restrict__ base) {
    if (threadIdx.x == 0) {
        int acc = 0;
        for (int e = 0; e < NEXP; ++e) { base[e] = acc; acc += counts[e]; }
        base[16] = acc;          // == 2*NTOK
        base[17] = acc + NTOK;
    }
}

// ---------------- GEMM1: h = silu(X W1^T) * (X W3^T) ----------------
// grid: (INTER/BN=11, NTOK/BM=32, 18), block 512 (8 waves, 4x2, each 64x64 x2)
template<bool XBF, bool WBF>
__global__ __launch_bounds__(512) void gemm1(
    const float* __restrict__ xf, const unsigned short* __restrict__ xb,
    const float* __restrict__ w1f, const float* __restrict__ w3f,
    const float* __restrict__ sw1f, const float* __restrict__ sw3f,
    const unsigned short* __restrict__ w1b, const unsigned short* __restrict__ w3b,
    const unsigned short* __restrict__ sw1b, const unsigned short* __restrict__ sw3b,
    const int* __restrict__ counts, const int* __restrict__ base,
    const int* __restrict__ toklist, unsigned short* __restrict__ hbuf) {
    const int e   = blockIdx.z;
    const int cnt = (e < NEXP) ? counts[e] : NTOK;
    const int m0  = blockIdx.y * BM;
    if (m0 >= cnt) return;
    const int n0  = blockIdx.x * BN;
    const size_t woff = (size_t)((e < NEXP) ? e : e - NEXP) * INTER * DIM;
    const int hbase = base[e];
    const int* tl = toklist + e * NTOK;

    __shared__ __attribute__((aligned(16))) unsigned short As[BM * BK];
    __shared__ __attribute__((aligned(16))) unsigned short B1s[BN * BK];
    __shared__ __attribute__((aligned(16))) unsigned short B3s[BN * BK];

    const int tid = threadIdx.x;
    const int w = tid >> 6, l = tid & 63;
    const int srow = l >> 2;        // 0..15 within a 16-row issue
    const int scol = (l & 3) * 8;   // element offset within 32-elem row

    int tokA[2];
#pragma unroll
    for (int j = 0; j < 2; ++j) {
        int row  = 32 * w + 16 * j + srow;
        int grow = m0 + row;
        int t;
        if (e >= NEXP) t = grow;
        else t = (grow < cnt) ? tl[grow] : 0;
        tokA[j] = t;
    }
    const int brow = n0 + 16 * w + srow;

    const unsigned short *gA0 = nullptr, *gA1 = nullptr, *gB1 = nullptr, *gB3 = nullptr;
    const float *gA0f = nullptr, *gA1f = nullptr, *gB1f = nullptr, *gB3f = nullptr;
    if constexpr (XBF) {
        gA0 = xb + (size_t)tokA[0] * DIM + scol;
        gA1 = xb + (size_t)tokA[1] * DIM + scol;
    } else {
        gA0f = xf + (size_t)tokA[0] * DIM + scol;
        gA1f = xf + (size_t)tokA[1] * DIM + scol;
    }
    if constexpr (WBF) {
        const unsigned short* b1 = ((e < NEXP) ? w1b : sw1b) + woff;
        const unsigned short* b3 = ((e < NEXP) ? w3b : sw3b) + woff;
        gB1 = b1 + (size_t)brow * DIM + scol;
        gB3 = b3 + (size_t)brow * DIM + scol;
    } else {
        const float* b1 = ((e < NEXP) ? w1f : sw1f) + woff;
        const float* b3 = ((e < NEXP) ? w3f : sw3f) + woff;
        gB1f = b1 + (size_t)brow * DIM + scol;
        gB3f = b3 + (size_t)brow * DIM + scol;
    }

    unsigned short* dA0 = As  + (size_t)(2 * w)     * 512;
    unsigned short* dA1 = As  + (size_t)(2 * w + 1) * 512;
    unsigned short* dB1 = B1s + (size_t)w * 512;
    unsigned short* dB3 = B3s + (size_t)w * 512;

    f32x4 acc1[4][4], acc3[4][4];
#pragma unroll
    for (int m = 0; m < 4; ++m)
#pragma unroll
        for (int n = 0; n < 4; ++n) {
            acc1[m][n] = (f32x4){0.f, 0.f, 0.f, 0.f};
            acc3[m][n] = (f32x4){0.f, 0.f, 0.f, 0.f};
        }

    const int wr = w >> 1, wc = w & 1;
    const int lr = l & 15, lk = (l >> 4) * 8;

    for (int k0 = 0; k0 < DIM; k0 += BK) {
        if constexpr (XBF) {
            gload16(gA0 + k0, dA0);
            gload16(gA1 + k0, dA1);
        } else {
            stage_f32(gA0f + k0, dA0 + l * 8);
            stage_f32(gA1f + k0, dA1 + l * 8);
        }
        if constexpr (WBF) {
            gload16(gB1 + k0, dB1);
            gload16(gB3 + k0, dB3);
        } else {
            stage_f32(gB1f + k0, dB1 + l * 8);
            stage_f32(gB3f + k0, dB3 + l * 8);
        }
        __syncthreads();
        bf16x8 af[4], b1q[4], b3q[4];
#pragma unroll
        for (int m = 0; m < 4; ++m)
            af[m] = *(const bf16x8*)(As + (wr * 64 + m * 16 + lr) * BK + lk);
#pragma unroll
        for (int n = 0; n < 4; ++n) {
            b1q[n] = *(const bf16x8*)(B1s + (wc * 64 + n * 16 + lr) * BK + lk);
            b3q[n] = *(const bf16x8*)(B3s + (wc * 64 + n * 16 + lr) * BK + lk);
        }
#pragma unroll
        for (int m = 0; m < 4; ++m)
#pragma unroll
            for (int n = 0; n < 4; ++n) {
                acc1[m][n] = __builtin_amdgcn_mfma_f32_16x16x32_bf16(af[m], b1q[n], acc1[m][n], 0, 0, 0);
                acc3[m][n] = __builtin_amdgcn_mfma_f32_16x16x32_bf16(af[m], b3q[n], acc3[m][n], 0, 0, 0);
            }
        __syncthreads();
    }
#pragma unroll
    for (int m = 0; m < 4; ++m) {
#pragma unroll
        for (int i = 0; i < 4; ++i) {
            int row  = wr * 64 + m * 16 + (l >> 4) * 4 + i;
            int grow = m0 + row;
            if (grow < cnt) {
                size_t ro = (size_t)(hbase + grow) * INTER;
#pragma unroll
                for (int n = 0; n < 4; ++n) {
                    int col = n0 + wc * 64 + n * 16 + lr;
                    float a = acc1[m][n][i];
                    float h = a / (1.f + __expf(-a)) * acc3[m][n][i];
                    hbuf[ro + col] = f2bf(h);
                }
            }
        }
    }
}

// ---------------- GEMM2: y += (h W2^T) * tokw ----------------
// grid: (DIM/BN=16, NTOK/BM=32, 18), block 512
template<bool WBF>
__global__ __launch_bounds__(512) void gemm2(
    const unsigned short* __restrict__ hbuf,
    const float* __restrict__ w2f, const float* __restrict__ sw2f,
    const unsigned short* __restrict__ w2b, const unsigned short* __restrict__ sw2b,
    const int* __restrict__ counts, const int* __restrict__ base,
    const int* __restrict__ toklist, const float* __restrict__ tokw,
    float* __restrict__ out) {
    const int e   = blockIdx.z;
    const int cnt = (e < NEXP) ? counts[e] : NTOK;
    const int m0  = blockIdx.y * BM;
    if (m0 >= cnt) return;
    const int n0  = blockIdx.x * BN;
    const int hbase = base[e];
    const size_t bstride = (e < NEXP) ? INTER : SINTER;

    const unsigned short* Bb = nullptr; const float* Bf = nullptr;
    if constexpr (WBF)
        Bb = (e < NEXP) ? w2b + (size_t)e * DIM * INTER : sw2b + (size_t)(e - NEXP) * INTER;
    else
        Bf = (e < NEXP) ? w2f + (size_t)e * DIM * INTER : sw2f + (size_t)(e - NEXP) * INTER;

    __shared__ __attribute__((aligned(16))) unsigned short As[BM * BK];
    __shared__ __attribute__((aligned(16))) unsigned short Bs[BN * BK];

    const int tid = threadIdx.x;
    const int w = tid >> 6, l = tid & 63;
    const int srow = l >> 2;
    const int scol = (l & 3) * 8;

    const unsigned short* gA0 = hbuf + (size_t)(hbase + m0 + 32 * w + srow) * INTER + scol;
    const unsigned short* gA1 = hbuf + (size_t)(hbase + m0 + 32 * w + 16 + srow) * INTER + scol;
    const int brow = n0 + 16 * w + srow;
    const unsigned short* gB = nullptr; const float* gBf = nullptr;
    if constexpr (WBF) gB  = Bb + (size_t)brow * bstride + scol;
    else               gBf = Bf + (size_t)brow * bstride + scol;

    unsigned short* dA0 = As + (size_t)(2 * w)     * 512;
    unsigned short* dA1 = As + (size_t)(2 * w + 1) * 512;
    unsigned short* dB  = Bs + (size_t)w * 512;

    f32x4 acc[4][4];
#pragma unroll
    for (int m = 0; m < 4; ++m)
#pragma unroll
        for (int n = 0; n < 4; ++n) acc[m][n] = (f32x4){0.f, 0.f, 0.f, 0.f};

    const int wr = w >> 1, wc = w & 1;
    const int lr = l & 15, lk = (l >> 4) * 8;

    for (int k0 = 0; k0 < INTER; k0 += BK) {
        gload16(gA0 + k0, dA0);
        gload16(gA1 + k0, dA1);
        if constexpr (WBF) gload16(gB + k0, dB);
        else               stage_f32(gBf + k0, dB + l * 8);
        __syncthreads();
        bf16x8 af[4], bq[4];
#pragma unroll
        for (int m = 0; m < 4; ++m)
            af[m] = *(const bf16x8*)(As + (wr * 64 + m * 16 + lr) * BK + lk);
#pragma unroll
        for (int n = 0; n < 4; ++n)
            bq[n] = *(const bf16x8*)(Bs + (wc * 64 + n * 16 + lr) * BK + lk);
#pragma unroll
        for (int m = 0; m < 4; ++m)
#pragma unroll
            for (int n = 0; n < 4; ++n)
                acc[m][n] = __builtin_amdgcn_mfma_f32_16x16x32_bf16(af[m], bq[n], acc[m][n], 0, 0, 0);
        __syncthreads();
    }
#pragma unroll
    for (int m = 0; m < 4; ++m) {
#pragma unroll
        for (int i = 0; i < 4; ++i) {
            int row  = wr * 64 + m * 16 + (l >> 4) * 4 + i;
            int grow = m0 + row;
            if (grow < cnt) {
                int tok; float wt;
                if (e < NEXP) { tok = toklist[e * NTOK + grow]; wt = tokw[e * NTOK + grow]; }
                else          { tok = grow; wt = 1.f; }
                float* orow = out + (size_t)tok * DIM + n0 + wc * 64 + lr;
#pragma unroll
                for (int n = 0; n < 4; ++n)
                    unsafeAtomicAdd(orow + n * 16, acc[m][n][i] * wt);
            }
        }
    }
}

extern "C" void kernel_launch(void* const* d_in, const int* in_sizes, int n_in,
                              void* d_out, int out_size, void* d_ws, size_t ws_size,
                              hipStream_t stream) {
    const float* x   = (const float*)d_in[0];
    const float* gw  = (const float*)d_in[1];
    const float* w1  = (const float*)d_in[2];
    const float* w2  = (const float*)d_in[3];
    const float* w3  = (const float*)d_in[4];
    const float* sw1 = (const float*)d_in[5];
    const float* sw2 = (const float*)d_in[6];
    const float* sw3 = (const float*)d_in[7];
    float* out = (float*)d_out;

    char* ws = (char*)d_ws;
    int*   counts  = (int*)ws;
    int*   basep   = (int*)(ws + 128);
    int*   toklist = (int*)(ws + 4096);
    float* tokw    = (float*)(ws + 4096 + (size_t)NEXP * NTOK * 4);
    unsigned short* hbuf = (unsigned short*)(ws + (2u << 20));

    const size_t hbytes = (size_t)4 * NTOK * INTER * 2;       // 92.3 MB
    const size_t offx   = (2ull << 20) + hbytes;
    const size_t xbytes = (size_t)NTOK * DIM * 2;             // 33.5 MB
    const size_t offw   = offx + xbytes;
    const size_t wB     = (size_t)NEXP * INTER * DIM * 2;     // 92.3 MB
    const size_t swB    = (size_t)SINTER * DIM * 2;           // 11.5 MB
    const size_t tier2_end = offw + 3 * wB + 3 * swB;         // ~439 MB

    int tier = (ws_size >= tier2_end) ? 2 : (ws_size >= offw ? 1 : 0);

    unsigned short* xb   = (unsigned short*)(ws + offx);
    unsigned short* w1b  = (unsigned short*)(ws + offw);
    unsigned short* w3b  = (unsigned short*)(ws + offw + wB);
    unsigned short* w2b  = (unsigned short*)(ws + offw + 2 * wB);
    unsigned short* sw1b = (unsigned short*)(ws + offw + 3 * wB);
    unsigned short* sw3b = (unsigned short*)(ws + offw + 3 * wB + swB);
    unsigned short* sw2b = (unsigned short*)(ws + offw + 3 * wB + 2 * swB);

    hipMemsetAsync(counts, 0, 64, stream);
    hipMemsetAsync(d_out, 0, (size_t)out_size * sizeof(float), stream);

    gate_topk<<<NTOK / 4, 256, 0, stream>>>(x, gw, counts, toklist, tokw);
    prefix_k<<<1, 64, 0, stream>>>(counts, basep);

    auto cast = [&](const float* s, unsigned short* d, long long n) {
        cast_bf16<<<(int)((n / 8 + 255) / 256), 256, 0, stream>>>(s, d, n);
    };
    if (tier >= 1) cast(x, xb, (long long)NTOK * DIM);
    if (tier == 2) {
        cast(w1, w1b, (long long)NEXP * INTER * DIM);
        cast(w3, w3b, (long long)NEXP * INTER * DIM);
        cast(w2, w2b, (long long)NEXP * INTER * DIM);
        cast(sw1, sw1b, (long long)SINTER * DIM);
        cast(sw3, sw3b, (long long)SINTER * DIM);
        cast(sw2, sw2b, (long long)SINTER * DIM);
    }

    dim3 g1(INTER / BN, NTOK / BM, 18);
    dim3 g2(DIM / BN, NTOK / BM, 18);
    if (tier == 2) {
        gemm1<true, true><<<g1, 512, 0, stream>>>(x, xb, w1, w3, sw1, sw3,
            w1b, w3b, sw1b, sw3b, counts, basep, toklist, hbuf);
        gemm2<true><<<g2, 512, 0, stream>>>(hbuf, w2, sw2, w2b, sw2b,
            counts, basep, toklist, tokw, out);
    } else if (tier == 1) {
        gemm1<true, false><<<g1, 512, 0, stream>>>(x, xb, w1, w3, sw1, sw3,
            w1b, w3b, sw1b, sw3b, counts, basep, toklist, hbuf);
        gemm2<false><<<g2, 512, 0, stream>>>(hbuf, w2, sw2, w2b, sw2b,
            counts, basep, toklist, tokw, out);
    } else {
        gemm1<false, false><<<g1, 512, 0, stream>>>(x, xb, w1, w3, sw1, sw3,
            w1b, w3b, sw1b, sw3b, counts, basep, toklist, hbuf);
        gemm2<false><<<g2, 512, 0, stream>>>(hbuf, w2, sw2, w2b, sw2b,
            counts, basep, toklist, tokw, out);
    }
}

// Round 3
// 1352.417 us; speedup vs baseline: 1.4064x; 1.0672x over previous
//
#include <hip/hip_runtime.h>
#include <hip/hip_bf16.h>

#define DIM 2048
#define INTER 1408
#define NEXP 16
#define NTOK 8192
#define SINTER 2816

typedef __attribute__((ext_vector_type(8))) short bf16x8;
typedef __attribute__((ext_vector_type(4))) float f32x4;
typedef __attribute__((ext_vector_type(8))) unsigned short u16x8;

__device__ __forceinline__ unsigned short f2bf(float f) {
    union { float f; unsigned u; } a; a.f = f;
    unsigned r = a.u + 0x7fffu + ((a.u >> 16) & 1u);
    return (unsigned short)(r >> 16);
}

__device__ __forceinline__ void gload16(const void* g, void* lds) {
    __builtin_amdgcn_global_load_lds(
        (const __attribute__((address_space(1))) void*)g,
        (__attribute__((address_space(3))) void*)lds, 16, 0, 0);
}

// ---------------- f32 -> bf16 cast ----------------
__global__ __launch_bounds__(256) void cast_bf16(const float* __restrict__ s,
                                                 unsigned short* __restrict__ d,
                                                 long long n) {
    long long i = ((long long)blockIdx.x * 256 + threadIdx.x) * 8;
    if (i >= n) return;
    float4 a = *(const float4*)(s + i), b = *(const float4*)(s + i + 4);
    u16x8 o = { f2bf(a.x), f2bf(a.y), f2bf(a.z), f2bf(a.w),
                f2bf(b.x), f2bf(b.y), f2bf(b.z), f2bf(b.w) };
    *(u16x8*)(d + i) = o;
}

// ---------------- gate + top2 routing ----------------
__global__ __launch_bounds__(256) void gate_topk(
    const float* __restrict__ x, const float* __restrict__ gw,
    int* __restrict__ counts, int* __restrict__ toklist, float* __restrict__ tokw) {
    int wave = threadIdx.x >> 6;
    int lane = threadIdx.x & 63;
    int tok  = blockIdx.x * 4 + wave;
    const float* xr = x + (size_t)tok * DIM;

    float part[NEXP];
#pragma unroll
    for (int e = 0; e < NEXP; ++e) part[e] = 0.f;
#pragma unroll
    for (int c = 0; c < DIM / 256; ++c) {
        float4 xv = *(const float4*)(xr + c * 256 + lane * 4);
#pragma unroll
        for (int e = 0; e < NEXP; ++e) {
            float4 g = *(const float4*)(gw + e * DIM + c * 256 + lane * 4);
            part[e] += xv.x * g.x + xv.y * g.y + xv.z * g.z + xv.w * g.w;
        }
    }
#pragma unroll
    for (int e = 0; e < NEXP; ++e) {
        float v = part[e];
#pragma unroll
        for (int off = 32; off; off >>= 1) v += __shfl_xor(v, off);
        part[e] = v;
    }
    float mx = part[0];
#pragma unroll
    for (int e = 1; e < NEXP; ++e) mx = fmaxf(mx, part[e]);
    float Z = 0.f;
#pragma unroll
    for (int e = 0; e < NEXP; ++e) Z += expf(part[e] - mx);
    int i1 = 0; float m1 = part[0];
#pragma unroll
    for (int e = 1; e < NEXP; ++e) if (part[e] > m1) { m1 = part[e]; i1 = e; }
    int i2 = -1; float m2 = -1e30f;
#pragma unroll
    for (int e = 0; e < NEXP; ++e) if (e != i1 && part[e] > m2) { m2 = part[e]; i2 = e; }
    if (lane == 0) {
        float w1v = expf(m1 - mx) / Z;
        float w2v = expf(m2 - mx) / Z;
        int p1 = atomicAdd(&counts[i1], 1);
        toklist[i1 * NTOK + p1] = tok; tokw[i1 * NTOK + p1] = w1v;
        int p2 = atomicAdd(&counts[i2], 1);
        toklist[i2 * NTOK + p2] = tok; tokw[i2 * NTOK + p2] = w2v;
    }
}

__global__ void prefix_k(const int* __restrict__ counts, int* __restrict__ base) {
    if (threadIdx.x == 0) {
        int acc = 0;
        for (int e = 0; e < NEXP; ++e) { base[e] = acc; acc += counts[e]; }
        base[16] = acc;          // == 2*NTOK
        base[17] = acc + NTOK;
    }
}

// swizzle helper: slot XOR within a 64B row (4 x 16B slots)
__device__ __forceinline__ int swz(int r) { return (r ^ (r >> 2)) & 3; }

// ================= GEMM1: h = silu(X W1^T) * (X W3^T) =================
// tile 256x128, BK half = 32. 8 waves 4Mx2N (per-wave 64x64, dual acc).
// pipeline: 4 half-buffers, depth-3 prefetch, counted vmcnt, raw s_barrier.
__global__ __launch_bounds__(512, 2) void gemm1(
    const unsigned short* __restrict__ xb,
    const unsigned short* __restrict__ w1b, const unsigned short* __restrict__ w3b,
    const unsigned short* __restrict__ sw1b, const unsigned short* __restrict__ sw3b,
    const int* __restrict__ counts, const int* __restrict__ base,
    const int* __restrict__ toklist, unsigned short* __restrict__ hbuf) {
    const int e   = blockIdx.z;
    const int cnt = (e < NEXP) ? counts[e] : NTOK;
    const int m0  = blockIdx.y * 256;
    if (m0 >= cnt) return;
    const int n0  = blockIdx.x * 128;
    const size_t woff = (size_t)((e < NEXP) ? e : e - NEXP) * INTER * DIM;
    const unsigned short* B1 = ((e < NEXP) ? w1b : sw1b) + woff;
    const unsigned short* B3 = ((e < NEXP) ? w3b : sw3b) + woff;
    const int hbase = base[e];
    const int* tl = toklist + e * NTOK;

    __shared__ __attribute__((aligned(16))) unsigned short As[4][8192];   // 64 KB
    __shared__ __attribute__((aligned(16))) unsigned short B1s[4][4096];  // 32 KB
    __shared__ __attribute__((aligned(16))) unsigned short B3s[4][4096];  // 32 KB

    const int tid = threadIdx.x;
    const int w = tid >> 6, l = tid & 63;
    const int wr = w >> 1, wc = w & 1;
    const int lr = l & 15, hi = l >> 4;

    // ---- staging setup (LDS dest linear; global source pre-swizzled) ----
    const int row0 = tid >> 2, row1 = row0 + 128;   // A rows; B row = row0
    const int c0 = (tid & 3) ^ swz(row0);           // swz(row1)==swz(row0)
    int g0 = m0 + row0, g1 = m0 + row1;
    int t0, t1;
    if (e < NEXP) { t0 = (g0 < cnt) ? tl[g0] : 0; t1 = (g1 < cnt) ? tl[g1] : 0; }
    else          { t0 = g0; t1 = g1; }
    const unsigned short* aSrc0 = xb + (size_t)t0 * DIM + c0 * 8;
    const unsigned short* aSrc1 = xb + (size_t)t1 * DIM + c0 * 8;
    const unsigned short* b1Src = B1 + (size_t)(n0 + row0) * DIM + c0 * 8;
    const unsigned short* b3Src = B3 + (size_t)(n0 + row0) * DIM + c0 * 8;

    // ---- read-side byte offsets (swizzled) ----
    int aoff[4], boff[4];
#pragma unroll
    for (int m = 0; m < 4; ++m) {
        int r = wr * 64 + m * 16 + lr;
        aoff[m] = r * 64 + ((swz(r) ^ hi) << 4);
    }
#pragma unroll
    for (int n = 0; n < 4; ++n) {
        int r = wc * 64 + n * 16 + lr;
        boff[n] = r * 64 + ((swz(r) ^ hi) << 4);
    }

    f32x4 acc1[4][4], acc3[4][4];
#pragma unroll
    for (int m = 0; m < 4; ++m)
#pragma unroll
        for (int n = 0; n < 4; ++n) {
            acc1[m][n] = (f32x4){0.f, 0.f, 0.f, 0.f};
            acc3[m][n] = (f32x4){0.f, 0.f, 0.f, 0.f};
        }

    const int H = DIM / 32;   // 64 half-steps

    auto STAGE = [&](int hh) {
        int hb = hh & 3;
        int kc = hh * 32;
        gload16(aSrc0 + kc, &As[hb][tid * 8]);
        gload16(aSrc1 + kc, &As[hb][4096 + tid * 8]);
        gload16(b1Src + kc, &B1s[hb][tid * 8]);
        gload16(b3Src + kc, &B3s[hb][tid * 8]);
    };

    STAGE(0); STAGE(1); STAGE(2);
    asm volatile("s_waitcnt vmcnt(8)" ::: "memory");   // half 0 complete
    __builtin_amdgcn_s_barrier();

    for (int h = 0; h < H; ++h) {
        const int hb = h & 3;
        // ds_read current half's fragments (swizzled offsets)
        bf16x8 af[4], b1f[4], b3f[4];
#pragma unroll
        for (int m = 0; m < 4; ++m)
            af[m] = *(const bf16x8*)((const char*)&As[hb][0] + aoff[m]);
#pragma unroll
        for (int n = 0; n < 4; ++n) {
            b1f[n] = *(const bf16x8*)((const char*)&B1s[hb][0] + boff[n]);
            b3f[n] = *(const bf16x8*)((const char*)&B3s[hb][0] + boff[n]);
        }
        // issue prefetch depth-3
        if (h + 3 < H) {
            STAGE(h + 3);
            asm volatile("s_waitcnt vmcnt(8)" ::: "memory");   // half h+1 ready
        } else if (h == H - 3) {
            asm volatile("s_waitcnt vmcnt(4)" ::: "memory");
        } else if (h == H - 2) {
            asm volatile("s_waitcnt vmcnt(0)" ::: "memory");
        }
        __builtin_amdgcn_s_barrier();
        asm volatile("s_waitcnt lgkmcnt(0)" ::: "memory");
        __builtin_amdgcn_sched_barrier(0);
        __builtin_amdgcn_s_setprio(1);
#pragma unroll
        for (int m = 0; m < 4; ++m)
#pragma unroll
            for (int n = 0; n < 4; ++n) {
                acc1[m][n] = __builtin_amdgcn_mfma_f32_16x16x32_bf16(af[m], b1f[n], acc1[m][n], 0, 0, 0);
                acc3[m][n] = __builtin_amdgcn_mfma_f32_16x16x32_bf16(af[m], b3f[n], acc3[m][n], 0, 0, 0);
            }
        __builtin_amdgcn_s_setprio(0);
        __builtin_amdgcn_s_barrier();
    }

    // epilogue: h = silu(c1)*c3 -> bf16 scratch
#pragma unroll
    for (int m = 0; m < 4; ++m) {
#pragma unroll
        for (int i = 0; i < 4; ++i) {
            int row  = wr * 64 + m * 16 + hi * 4 + i;
            int grow = m0 + row;
            if (grow < cnt) {
                size_t ro = (size_t)(hbase + grow) * INTER;
#pragma unroll
                for (int n = 0; n < 4; ++n) {
                    int col = n0 + wc * 64 + n * 16 + lr;
                    float a = acc1[m][n][i];
                    float hv = a / (1.f + __expf(-a)) * acc3[m][n][i];
                    hbuf[ro + col] = f2bf(hv);
                }
            }
        }
    }
}

// ================= GEMM2: y += (h W2^T) * tokw =================
// tile 256x256, 8 waves 2Mx4N (per-wave 128x64). Same pipeline.
__global__ __launch_bounds__(512, 2) void gemm2(
    const unsigned short* __restrict__ hbuf,
    const unsigned short* __restrict__ w2b, const unsigned short* __restrict__ sw2b,
    const int* __restrict__ counts, const int* __restrict__ base,
    const int* __restrict__ toklist, const float* __restrict__ tokw,
    float* __restrict__ out) {
    const int e   = blockIdx.z;
    const int cnt = (e < NEXP) ? counts[e] : NTOK;
    const int m0  = blockIdx.y * 256;
    if (m0 >= cnt) return;
    const int n0  = blockIdx.x * 256;
    const int hbase = base[e];
    const size_t bstride = (e < NEXP) ? INTER : SINTER;
    const unsigned short* Bb = (e < NEXP) ? w2b + (size_t)e * DIM * INTER
                                          : sw2b + (size_t)(e - NEXP) * INTER;

    __shared__ __attribute__((aligned(16))) unsigned short Ah[4][8192];   // 64 KB
    __shared__ __attribute__((aligned(16))) unsigned short Bh[4][8192];   // 64 KB

    const int tid = threadIdx.x;
    const int w = tid >> 6, l = tid & 63;
    const int wr = w >> 2, wc = w & 3;
    const int lr = l & 15, hi = l >> 4;

    const int row0 = tid >> 2, row1 = row0 + 128;
    const int c0 = (tid & 3) ^ swz(row0);
    const unsigned short* aSrc0 = hbuf + (size_t)(hbase + m0 + row0) * INTER + c0 * 8;
    const unsigned short* aSrc1 = hbuf + (size_t)(hbase + m0 + row1) * INTER + c0 * 8;
    const unsigned short* bSrc0 = Bb + (size_t)(n0 + row0) * bstride + c0 * 8;
    const unsigned short* bSrc1 = Bb + (size_t)(n0 + row1) * bstride + c0 * 8;

    int aoff[8], boff[4];
#pragma unroll
    for (int m = 0; m < 8; ++m) {
        int r = wr * 128 + m * 16 + lr;
        aoff[m] = r * 64 + ((swz(r) ^ hi) << 4);
    }
#pragma unroll
    for (int n = 0; n < 4; ++n) {
        int r = wc * 64 + n * 16 + lr;
        boff[n] = r * 64 + ((swz(r) ^ hi) << 4);
    }

    f32x4 acc[8][4];
#pragma unroll
    for (int m = 0; m < 8; ++m)
#pragma unroll
        for (int n = 0; n < 4; ++n) acc[m][n] = (f32x4){0.f, 0.f, 0.f, 0.f};

    const int H = INTER / 32;   // 44 half-steps

    auto STAGE = [&](int hh) {
        int hb = hh & 3;
        int kc = hh * 32;
        gload16(aSrc0 + kc, &Ah[hb][tid * 8]);
        gload16(aSrc1 + kc, &Ah[hb][4096 + tid * 8]);
        gload16(bSrc0 + kc, &Bh[hb][tid * 8]);
        gload16(bSrc1 + kc, &Bh[hb][4096 + tid * 8]);
    };

    STAGE(0); STAGE(1); STAGE(2);
    asm volatile("s_waitcnt vmcnt(8)" ::: "memory");
    __builtin_amdgcn_s_barrier();

    for (int h = 0; h < H; ++h) {
        const int hb = h & 3;
        bf16x8 af[8], bf[4];
#pragma unroll
        for (int m = 0; m < 8; ++m)
            af[m] = *(const bf16x8*)((const char*)&Ah[hb][0] + aoff[m]);
#pragma unroll
        for (int n = 0; n < 4; ++n)
            bf[n] = *(const bf16x8*)((const char*)&Bh[hb][0] + boff[n]);
        if (h + 3 < H) {
            STAGE(h + 3);
            asm volatile("s_waitcnt vmcnt(8)" ::: "memory");
        } else if (h == H - 3) {
            asm volatile("s_waitcnt vmcnt(4)" ::: "memory");
        } else if (h == H - 2) {
            asm volatile("s_waitcnt vmcnt(0)" ::: "memory");
        }
        __builtin_amdgcn_s_barrier();
        asm volatile("s_waitcnt lgkmcnt(0)" ::: "memory");
        __builtin_amdgcn_sched_barrier(0);
        __builtin_amdgcn_s_setprio(1);
#pragma unroll
        for (int m = 0; m < 8; ++m)
#pragma unroll
            for (int n = 0; n < 4; ++n)
                acc[m][n] = __builtin_amdgcn_mfma_f32_16x16x32_bf16(af[m], bf[n], acc[m][n], 0, 0, 0);
        __builtin_amdgcn_s_setprio(0);
        __builtin_amdgcn_s_barrier();
    }

    // epilogue: weighted atomic scatter into out
#pragma unroll
    for (int m = 0; m < 8; ++m) {
#pragma unroll
        for (int i = 0; i < 4; ++i) {
            int row  = wr * 128 + m * 16 + hi * 4 + i;
            int grow = m0 + row;
            if (grow < cnt) {
                int tok; float wt;
                if (e < NEXP) { tok = toklist[e * NTOK + grow]; wt = tokw[e * NTOK + grow]; }
                else          { tok = grow; wt = 1.f; }
                float* orow = out + (size_t)tok * DIM + n0 + wc * 64 + lr;
#pragma unroll
                for (int n = 0; n < 4; ++n)
                    unsafeAtomicAdd(orow + n * 16, acc[m][n][i] * wt);
            }
        }
    }
}

extern "C" void kernel_launch(void* const* d_in, const int* in_sizes, int n_in,
                              void* d_out, int out_size, void* d_ws, size_t ws_size,
                              hipStream_t stream) {
    const float* x   = (const float*)d_in[0];
    const float* gw  = (const float*)d_in[1];
    const float* w1  = (const float*)d_in[2];
    const float* w2  = (const float*)d_in[3];
    const float* w3  = (const float*)d_in[4];
    const float* sw1 = (const float*)d_in[5];
    const float* sw2 = (const float*)d_in[6];
    const float* sw3 = (const float*)d_in[7];
    float* out = (float*)d_out;

    char* ws = (char*)d_ws;
    int*   counts  = (int*)ws;
    int*   basep   = (int*)(ws + 128);
    int*   toklist = (int*)(ws + 4096);
    float* tokw    = (float*)(ws + 4096 + (size_t)NEXP * NTOK * 4);
    unsigned short* hbuf = (unsigned short*)(ws + (2u << 20));

    const size_t hbytes = (size_t)4 * NTOK * INTER * 2;       // 92.3 MB
    const size_t offx   = (2ull << 20) + hbytes;
    const size_t xbytes = (size_t)NTOK * DIM * 2;             // 33.5 MB
    const size_t offw   = offx + xbytes;
    const size_t wB     = (size_t)NEXP * INTER * DIM * 2;     // 92.3 MB
    const size_t swB    = (size_t)SINTER * DIM * 2;           // 11.5 MB

    unsigned short* xb   = (unsigned short*)(ws + offx);
    unsigned short* w1b  = (unsigned short*)(ws + offw);
    unsigned short* w3b  = (unsigned short*)(ws + offw + wB);
    unsigned short* w2b  = (unsigned short*)(ws + offw + 2 * wB);
    unsigned short* sw1b = (unsigned short*)(ws + offw + 3 * wB);
    unsigned short* sw3b = (unsigned short*)(ws + offw + 3 * wB + swB);
    unsigned short* sw2b = (unsigned short*)(ws + offw + 3 * wB + 2 * swB);

    hipMemsetAsync(counts, 0, 64, stream);
    hipMemsetAsync(d_out, 0, (size_t)out_size * sizeof(float), stream);

    gate_topk<<<NTOK / 4, 256, 0, stream>>>(x, gw, counts, toklist, tokw);
    prefix_k<<<1, 64, 0, stream>>>(counts, basep);

    auto cast = [&](const float* s, unsigned short* d, long long n) {
        cast_bf16<<<(int)((n / 8 + 255) / 256), 256, 0, stream>>>(s, d, n);
    };
    cast(x, xb, (long long)NTOK * DIM);
    cast(w1, w1b, (long long)NEXP * INTER * DIM);
    cast(w3, w3b, (long long)NEXP * INTER * DIM);
    cast(w2, w2b, (long long)NEXP * INTER * DIM);
    cast(sw1, sw1b, (long long)SINTER * DIM);
    cast(sw3, sw3b, (long long)SINTER * DIM);
    cast(sw2, sw2b, (long long)SINTER * DIM);

    gemm1<<<dim3(INTER / 128, NTOK / 256, 18), 512, 0, stream>>>(
        xb, w1b, w3b, sw1b, sw3b, counts, basep, toklist, hbuf);
    gemm2<<<dim3(DIM / 256, NTOK / 256, 18), 512, 0, stream>>>(
        hbuf, w2b, sw2b, counts, basep, toklist, tokw, out);
}